// Round 3
// baseline (22122.530 us; speedup 1.0000x reference)
//
#include <hip/hip_runtime.h>
#include <math.h>

#define BB 256   // batch
#define TT 512   // encoder seq len
#define DD 64    // state dim
#define HH 512   // hidden dim
#define FF 32    // fc_seq_len (decoder steps)

__device__ __forceinline__ float sigmoidf_(float x) { return 1.0f / (1.0f + __expf(-x)); }

// Fused GRU cell step. Grid: (HH/32, BB/16), block 256.
// Each wg computes h_new tile [16 batch x 32 hidden].
// acc_r/acc_z take x-part + h-part combined; gate n keeps i_n (x-part) and
// h_n (h-part) separate because n = tanh(i_n + r * h_n).
#define GRU_TILE_LOOP(N0, N1)                                              \
    _Pragma("unroll")                                                      \
    for (int k = 0; k < 32; k += 2) {                                      \
        const float2 a0 = *(const float2*)&hs[bb][k];                      \
        const float2 a1 = *(const float2*)&hs[bb + 8][k];                  \
        const float2 w0 = *(const float2*)&ws[jj][k];                      \
        const float2 w1 = *(const float2*)&ws[32 + jj][k];                 \
        const float2 w2 = *(const float2*)&ws[64 + jj][k];                 \
        acc_r0 = fmaf(a0.x, w0.x, acc_r0); acc_r0 = fmaf(a0.y, w0.y, acc_r0); \
        acc_z0 = fmaf(a0.x, w1.x, acc_z0); acc_z0 = fmaf(a0.y, w1.y, acc_z0); \
        N0     = fmaf(a0.x, w2.x, N0);     N0     = fmaf(a0.y, w2.y, N0);     \
        acc_r1 = fmaf(a1.x, w0.x, acc_r1); acc_r1 = fmaf(a1.y, w0.y, acc_r1); \
        acc_z1 = fmaf(a1.x, w1.x, acc_z1); acc_z1 = fmaf(a1.y, w1.y, acc_z1); \
        N1     = fmaf(a1.x, w2.x, N1);     N1     = fmaf(a1.y, w2.y, N1);     \
    }

__global__ __launch_bounds__(256) void gru_step(
    const float* __restrict__ x, int x_stride,      // [BB, DD] rows at x_stride
    const float* __restrict__ h,                    // [BB, HH] or nullptr (== zeros)
    const float* __restrict__ W_ih,                 // [3*HH, DD]
    const float* __restrict__ W_hh,                 // [3*HH, HH]
    const float* __restrict__ b_ih,                 // [3*HH]
    const float* __restrict__ b_hh,                 // [3*HH]
    float* __restrict__ h_out,                      // [BB, HH]
    float* __restrict__ h_out2, int h_out2_stride)  // optional extra write (h_seq)
{
    __shared__ __align__(16) float hs[16][34];
    __shared__ __align__(16) float ws[96][34];

    const int tid = threadIdx.x;
    const int jj = tid & 31;   // hidden col within tile
    const int bb = tid >> 5;   // 0..7 (handles rows bb and bb+8)
    const int j0 = blockIdx.x * 32;
    const int b0 = blockIdx.y * 16;

    float acc_r0 = 0.f, acc_z0 = 0.f, ghn0 = 0.f, gin0 = 0.f;
    float acc_r1 = 0.f, acc_z1 = 0.f, ghn1 = 0.f, gin1 = 0.f;

    // ---------- x part: K = DD = 64 ----------
    for (int kt = 0; kt < DD; kt += 32) {
        {   // stage x tile [16][32]
            const int r = tid >> 4, c2 = (tid & 15) * 2;
            *(float2*)&hs[r][c2] = *(const float2*)&x[(b0 + r) * x_stride + kt + c2];
        }
        #pragma unroll
        for (int i = 0; i < 6; ++i) {   // stage 96 rows x 32 of W_ih
            const int idx = i * 256 + tid;
            const int r = idx >> 4, c2 = (idx & 15) * 2;
            const int g = r >> 5;
            const int row = g * HH + j0 + (r & 31);
            *(float2*)&ws[r][c2] = *(const float2*)&W_ih[row * DD + kt + c2];
        }
        __syncthreads();
        GRU_TILE_LOOP(gin0, gin1)
        __syncthreads();
    }

    // ---------- h part: K = HH = 512 ----------
    if (h != nullptr) {
        for (int kt = 0; kt < HH; kt += 32) {
            {
                const int r = tid >> 4, c2 = (tid & 15) * 2;
                *(float2*)&hs[r][c2] = *(const float2*)&h[(b0 + r) * HH + kt + c2];
            }
            #pragma unroll
            for (int i = 0; i < 6; ++i) {
                const int idx = i * 256 + tid;
                const int r = idx >> 4, c2 = (idx & 15) * 2;
                const int g = r >> 5;
                const int row = g * HH + j0 + (r & 31);
                *(float2*)&ws[r][c2] = *(const float2*)&W_hh[row * HH + kt + c2];
            }
            __syncthreads();
            GRU_TILE_LOOP(ghn0, ghn1)
            __syncthreads();
        }
    }

    // ---------- epilogue ----------
    const int j = j0 + jj;
    const float br  = b_ih[j] + b_hh[j];
    const float bz  = b_ih[HH + j] + b_hh[HH + j];
    const float bin = b_ih[2 * HH + j];
    const float bhn = b_hh[2 * HH + j];

    {
        const int b = b0 + bb;
        const float r = sigmoidf_(acc_r0 + br);
        const float z = sigmoidf_(acc_z0 + bz);
        const float hold = h ? h[b * HH + j] : 0.f;
        const float n = tanhf(gin0 + bin + r * (ghn0 + bhn));
        const float hn = (1.f - z) * n + z * hold;
        h_out[b * HH + j] = hn;
        if (h_out2) h_out2[b * h_out2_stride + j] = hn;
    }
    {
        const int b = b0 + bb + 8;
        const float r = sigmoidf_(acc_r1 + br);
        const float z = sigmoidf_(acc_z1 + bz);
        const float hold = h ? h[b * HH + j] : 0.f;
        const float n = tanhf(gin1 + bin + r * (ghn1 + bhn));
        const float hn = (1.f - z) * n + z * hold;
        h_out[b * HH + j] = hn;
        if (h_out2) h_out2[b * h_out2_stride + j] = hn;
    }
}

// a[b,j] = relu(sum_k h[b,k]*w[j,k] + bias[j]). Grid (HH/32, BB/16), block 256.
__global__ __launch_bounds__(256) void fc1_relu(
    const float* __restrict__ h, const float* __restrict__ w,
    const float* __restrict__ bias, float* __restrict__ out)
{
    __shared__ __align__(16) float hs[16][34];
    __shared__ __align__(16) float ws[32][34];
    const int tid = threadIdx.x;
    const int jj = tid & 31, bb = tid >> 5;
    const int j0 = blockIdx.x * 32, b0 = blockIdx.y * 16;
    float a0 = 0.f, a1 = 0.f;

    for (int kt = 0; kt < HH; kt += 32) {
        {
            const int r = tid >> 4, c2 = (tid & 15) * 2;
            *(float2*)&hs[r][c2] = *(const float2*)&h[(b0 + r) * HH + kt + c2];
        }
        #pragma unroll
        for (int i = 0; i < 2; ++i) {   // 32 rows x 32
            const int idx = i * 256 + tid;
            const int r = idx >> 4, c2 = (idx & 15) * 2;
            *(float2*)&ws[r][c2] = *(const float2*)&w[(j0 + r) * HH + kt + c2];
        }
        __syncthreads();
        #pragma unroll
        for (int k = 0; k < 32; k += 2) {
            const float2 h0 = *(const float2*)&hs[bb][k];
            const float2 h1 = *(const float2*)&hs[bb + 8][k];
            const float2 w0 = *(const float2*)&ws[jj][k];
            a0 = fmaf(h0.x, w0.x, a0); a0 = fmaf(h0.y, w0.y, a0);
            a1 = fmaf(h1.x, w0.x, a1); a1 = fmaf(h1.y, w0.y, a1);
        }
        __syncthreads();
    }
    const float b = bias[j0 + jj];
    out[(b0 + bb) * HH + j0 + jj]     = fmaxf(a0 + b, 0.f);
    out[(b0 + bb + 8) * HH + j0 + jj] = fmaxf(a1 + b, 0.f);
}

// s[b,d] = sum_k a[b,k]*w[d,k] + bias[d]; writes sBuf and s_seq slice.
// Grid (BB/4), block 256: d = tid&63, bb = tid>>6.
__global__ __launch_bounds__(256) void fc2_out(
    const float* __restrict__ a, const float* __restrict__ w,
    const float* __restrict__ bias, float* __restrict__ s_buf,
    float* __restrict__ s_out, int s_out_stride)
{
    __shared__ __align__(16) float as[4][34];
    __shared__ __align__(16) float ws[64][34];
    const int tid = threadIdx.x;
    const int d = tid & 63, bb = tid >> 6;
    const int b0 = blockIdx.x * 4;
    float acc = 0.f;

    for (int kt = 0; kt < HH; kt += 32) {
        if (tid < 64) {
            const int r = tid >> 4, c2 = (tid & 15) * 2;
            *(float2*)&as[r][c2] = *(const float2*)&a[(b0 + r) * HH + kt + c2];
        }
        #pragma unroll
        for (int i = 0; i < 4; ++i) {   // 64 rows x 32
            const int idx = i * 256 + tid;
            const int r = idx >> 4, c2 = (idx & 15) * 2;
            *(float2*)&ws[r][c2] = *(const float2*)&w[r * HH + kt + c2];
        }
        __syncthreads();
        #pragma unroll
        for (int k = 0; k < 32; k += 2) {
            const float2 av = *(const float2*)&as[bb][k];
            const float2 wv = *(const float2*)&ws[d][k];
            acc = fmaf(av.x, wv.x, acc); acc = fmaf(av.y, wv.y, acc);
        }
        __syncthreads();
    }
    const float v = acc + bias[d];
    const int b = b0 + bb;
    s_buf[b * DD + d] = v;
    s_out[b * s_out_stride + d] = v;
}

extern "C" void kernel_launch(void* const* d_in, const int* in_sizes, int n_in,
                              void* d_out, int out_size, void* d_ws, size_t ws_size,
                              hipStream_t stream) {
    const float* state_seq = (const float*)d_in[0];  // [256,512,64]
    const float* W_ih  = (const float*)d_in[1];      // [1536,64]
    const float* W_hh  = (const float*)d_in[2];      // [1536,512]
    const float* b_ih  = (const float*)d_in[3];
    const float* b_hh  = (const float*)d_in[4];
    const float* fc1_w = (const float*)d_in[5];      // [512,512]
    const float* fc1_b = (const float*)d_in[6];
    const float* fc2_w = (const float*)d_in[7];      // [64,512]
    const float* fc2_b = (const float*)d_in[8];

    float* out_s = (float*)d_out;                    // [256, 32, 64]
    float* out_h = out_s + BB * FF * DD;             // [256, 32, 512]

    float* hA   = (float*)d_ws;
    float* hB   = hA + BB * HH;
    float* aBuf = hB + BB * HH;
    float* sBuf = aBuf + BB * HH;

    const dim3 blk(256);
    const dim3 gruGrid(HH / 32, BB / 16);

    // ---- encoder: 512 GRU steps from h0 = 0 ----
    const float* hcur = nullptr;
    for (int t = 0; t < TT; ++t) {
        float* hout = (t & 1) ? hB : hA;
        // final encoder hidden == h_seq[:, 0, :]
        float* hout2 = (t == TT - 1) ? out_h : nullptr;
        gru_step<<<gruGrid, blk, 0, stream>>>(state_seq + t * DD, TT * DD, hcur,
                                              W_ih, W_hh, b_ih, b_hh,
                                              hout, hout2, FF * HH);
        hcur = hout;
    }

    // ---- decoder: 32 fc_predicts, 31 GRU steps ----
    for (int t = 0; t < FF; ++t) {
        fc1_relu<<<dim3(HH / 32, BB / 16), blk, 0, stream>>>(hcur, fc1_w, fc1_b, aBuf);
        fc2_out<<<dim3(BB / 4), blk, 0, stream>>>(aBuf, fc2_w, fc2_b, sBuf,
                                                  out_s + t * DD, FF * DD);
        if (t < FF - 1) {
            float* hout = (hcur == hA) ? hB : hA;
            gru_step<<<gruGrid, blk, 0, stream>>>(sBuf, DD, hcur,
                                                  W_ih, W_hh, b_ih, b_hh,
                                                  hout, out_h + (t + 1) * HH, FF * HH);
            hcur = hout;
        }
    }
}